// Round 2
// baseline (607.713 us; speedup 1.0000x reference)
//
#include <hip/hip_runtime.h>
#include <hip/hip_bf16.h>

static constexpr int E_ = 5000;
static constexpr int N_ = 200000;
static constexpr int D_ = 128;
// 1 / (3 * sqrt(128))
static constexpr float INV_ = 0.029462782549439484f;

// Zero-fill both adjacency matrices (fp32) and write 1.0 on each diagonal.
// Each thread stores one 16B chunk (4 floats). E*E = 25e6 is divisible by 4,
// so a chunk never straddles the two graphs.
__global__ __launch_bounds__(256) void init_kernel(float* __restrict__ out,
                                                   int nchunks) {
    int c = blockIdx.x * 256 + threadIdx.x;
    if (c >= nchunks) return;
    int base = c * 4;                  // flat float index, < 50e6 (fits int)
    int local = base % (E_ * E_);      // position within one graph's E*E
    float4 v = make_float4(0.f, 0.f, 0.f, 0.f);
    // diagonal elements sit at local = i*(E+1); at most one per 4-chunk
    int r = local % (E_ + 1);
    int k = (r == 0) ? 0 : (E_ + 1) - r;
    if (k == 0) v.x = 1.0f;
    else if (k == 1) v.y = 1.0f;
    else if (k == 2) v.z = 1.0f;
    else if (k == 3) v.w = 1.0f;
    reinterpret_cast<float4*>(out)[c] = v;
}

// One 64-lane wave per triple. Lane l handles dims 2l, 2l+1 (8B coalesced).
__global__ __launch_bounds__(256) void triple_kernel(
        const float* __restrict__ ent,   // [E, D] f32
        const float* __restrict__ rel,   // [R, D] f32
        const float* __restrict__ relw,  // [R]    f32
        const float* __restrict__ conf,  // [E, E] f32
        const float* __restrict__ imp,   // [E, E] f32
        const float* __restrict__ pca,   // [E, E] f32
        const int* __restrict__ head,
        const int* __restrict__ tail,
        const int* __restrict__ ridx,
        float* __restrict__ out)         // [E, E] f32
{
    int gtid = blockIdx.x * 256 + threadIdx.x;
    int w = gtid >> 6;          // triple index (wave-uniform)
    int lane = gtid & 63;
    if (w >= N_) return;

    int h = head[w];
    int t = tail[w];
    int r = ridx[w];

    int d0 = lane * 2;
    float2 hv = *reinterpret_cast<const float2*>(ent + h * D_ + d0);
    float2 tv = *reinterpret_cast<const float2*>(ent + t * D_ + d0);
    float2 rv = *reinterpret_cast<const float2*>(rel + r * D_ + d0);

    float s = fabsf(hv.x + rv.x - tv.x)
            + fabsf(hv.y + rv.y - tv.y);

    // wave-64 butterfly reduce
    #pragma unroll
    for (int off = 32; off > 0; off >>= 1)
        s += __shfl_xor(s, off, 64);

    if (lane == 0) {
        float tvs = 1.0f - s * INV_;
        int pos = h * E_ + t;                    // < 25e6, fits int
        float val = conf[pos] * imp[pos]
                  * (0.3f * pca[pos] + 0.3f * tvs + 0.4f * relw[r]);
        if (h == t) val += 1.0f;                 // overwrite init's diagonal 1.0
        out[pos] = val;                          // unique (h,t) -> plain store
    }
}

extern "C" void kernel_launch(void* const* d_in, const int* in_sizes, int n_in,
                              void* d_out, int out_size, void* d_ws, size_t ws_size,
                              hipStream_t stream) {
    const float* ent_sr  = (const float*)d_in[0];
    const float* ent_tg  = (const float*)d_in[1];
    const float* rel_sr  = (const float*)d_in[2];
    const float* rel_tg  = (const float*)d_in[3];
    const float* relw_sr = (const float*)d_in[4];
    const float* relw_tg = (const float*)d_in[5];
    const float* conf_sr = (const float*)d_in[6];
    const float* imp_sr  = (const float*)d_in[7];
    const float* pca_sr  = (const float*)d_in[8];
    const float* conf_tg = (const float*)d_in[9];
    const float* imp_tg  = (const float*)d_in[10];
    const float* pca_tg  = (const float*)d_in[11];
    const int* head_sr = (const int*)d_in[12];
    const int* tail_sr = (const int*)d_in[13];
    const int* rel_i_sr = (const int*)d_in[14];
    const int* head_tg = (const int*)d_in[15];
    const int* tail_tg = (const int*)d_in[16];
    const int* rel_i_tg = (const int*)d_in[17];

    float* out = (float*)d_out;

    const int total = 2 * E_ * E_;           // 50,000,000 floats
    const int nchunks = total / 4;           // 12,500,000
    int init_blocks = (nchunks + 255) / 256;
    init_kernel<<<init_blocks, 256, 0, stream>>>(out, nchunks);

    int tri_blocks = (N_ * 64 + 255) / 256;  // 4 triples per 256-thread block
    triple_kernel<<<tri_blocks, 256, 0, stream>>>(
        ent_sr, rel_sr, relw_sr, conf_sr, imp_sr, pca_sr,
        head_sr, tail_sr, rel_i_sr, out);
    triple_kernel<<<tri_blocks, 256, 0, stream>>>(
        ent_tg, rel_tg, relw_tg, conf_tg, imp_tg, pca_tg,
        head_tg, tail_tg, rel_i_tg, out + (long long)E_ * E_);
}

// Round 3
// 598.128 us; speedup vs baseline: 1.0160x; 1.0160x over previous
//
#include <hip/hip_runtime.h>
#include <hip/hip_bf16.h>

static constexpr int E_ = 5000;
static constexpr int N_ = 200000;
static constexpr int D_ = 128;
// 1 / (3 * sqrt(128))
static constexpr float INV_ = 0.029462782549439484f;

// Zero-fill both adjacency matrices (fp32) and write 1.0 on each diagonal.
// Each thread stores 64 B (16 floats = 4 x float4). E*E = 25e6 is divisible
// by 16, so a chunk never straddles the two graphs. A 16-float chunk contains
// at most one diagonal element (diag stride is E+1 = 5001 > 16).
__global__ __launch_bounds__(256) void init_kernel(float* __restrict__ out,
                                                   int nthreads) {
    int c = blockIdx.x * 256 + threadIdx.x;
    if (c >= nthreads) return;
    int base = c * 16;                 // flat float index, < 50e6 (fits int)
    int local = base % (E_ * E_);      // position within one graph's E*E
    float v[16];
    #pragma unroll
    for (int i = 0; i < 16; ++i) v[i] = 0.f;
    int r = local % (E_ + 1);
    int k = (r == 0) ? 0 : (E_ + 1) - r;
    if (k < 16) v[k] = 1.0f;
    float4* dst = reinterpret_cast<float4*>(out + base);
    const float4* src = reinterpret_cast<const float4*>(v);
    #pragma unroll
    for (int i = 0; i < 4; ++i) dst[i] = src[i];
}

// 16 lanes per triple (4 triples per wave). Lane sub-index s in [0,16)
// handles dims 8s..8s+7 via two float4 loads. Covers BOTH graphs in one
// dispatch: triples [0,N) are sr, [N,2N) are tg. N % 4 == 0 so all 4
// triples in a wave belong to the same graph.
__global__ __launch_bounds__(256) void triple_kernel(
        const float* __restrict__ ent_a, const float* __restrict__ rel_a,
        const float* __restrict__ relw_a,
        const float* __restrict__ conf_a, const float* __restrict__ imp_a,
        const float* __restrict__ pca_a,
        const int* __restrict__ head_a, const int* __restrict__ tail_a,
        const int* __restrict__ ridx_a,
        const float* __restrict__ ent_b, const float* __restrict__ rel_b,
        const float* __restrict__ relw_b,
        const float* __restrict__ conf_b, const float* __restrict__ imp_b,
        const float* __restrict__ pca_b,
        const int* __restrict__ head_b, const int* __restrict__ tail_b,
        const int* __restrict__ ridx_b,
        float* __restrict__ out)         // [2, E, E] f32
{
    int gtid = blockIdx.x * 256 + threadIdx.x;
    int wave = gtid >> 6;
    int lane = gtid & 63;
    int sub  = lane & 15;               // lane within the 16-group
    int trip = wave * 4 + (lane >> 4);  // global triple id in [0, 2N)
    if (trip >= 2 * N_) return;

    bool gB = (trip >= N_);             // wave-uniform (N % 4 == 0)
    int  w  = gB ? (trip - N_) : trip;

    const float* ent  = gB ? ent_b  : ent_a;
    const float* rel  = gB ? rel_b  : rel_a;
    const float* relw = gB ? relw_b : relw_a;
    const float* conf = gB ? conf_b : conf_a;
    const float* imp  = gB ? imp_b  : imp_a;
    const float* pca  = gB ? pca_b  : pca_a;
    const int*  head  = gB ? head_b : head_a;
    const int*  tail  = gB ? tail_b : tail_a;
    const int*  ridx  = gB ? ridx_b : ridx_a;
    float* o = out + (gB ? (long long)E_ * E_ : 0);

    int h = head[w];
    int t = tail[w];
    int r = ridx[w];

    int d0 = sub * 8;
    const float4* hp = reinterpret_cast<const float4*>(ent + h * D_ + d0);
    const float4* tp = reinterpret_cast<const float4*>(ent + t * D_ + d0);
    const float4* rp = reinterpret_cast<const float4*>(rel + r * D_ + d0);
    float4 h0 = hp[0], h1 = hp[1];
    float4 t0 = tp[0], t1 = tp[1];
    float4 r0 = rp[0], r1 = rp[1];

    float s = fabsf(h0.x + r0.x - t0.x) + fabsf(h0.y + r0.y - t0.y)
            + fabsf(h0.z + r0.z - t0.z) + fabsf(h0.w + r0.w - t0.w)
            + fabsf(h1.x + r1.x - t1.x) + fabsf(h1.y + r1.y - t1.y)
            + fabsf(h1.z + r1.z - t1.z) + fabsf(h1.w + r1.w - t1.w);

    // reduce across the 16-lane group (xor masks < 16 stay in-group)
    s += __shfl_xor(s, 8, 64);
    s += __shfl_xor(s, 4, 64);
    s += __shfl_xor(s, 2, 64);
    s += __shfl_xor(s, 1, 64);

    if (sub == 0) {
        float tvs = 1.0f - s * INV_;
        int pos = h * E_ + t;                    // < 25e6, fits int
        float val = conf[pos] * imp[pos]
                  * (0.3f * pca[pos] + 0.3f * tvs + 0.4f * relw[r]);
        if (h == t) val += 1.0f;                 // overwrite init's diagonal 1.0
        o[pos] = val;                            // unique (h,t) -> plain store
    }
}

extern "C" void kernel_launch(void* const* d_in, const int* in_sizes, int n_in,
                              void* d_out, int out_size, void* d_ws, size_t ws_size,
                              hipStream_t stream) {
    const float* ent_sr  = (const float*)d_in[0];
    const float* ent_tg  = (const float*)d_in[1];
    const float* rel_sr  = (const float*)d_in[2];
    const float* rel_tg  = (const float*)d_in[3];
    const float* relw_sr = (const float*)d_in[4];
    const float* relw_tg = (const float*)d_in[5];
    const float* conf_sr = (const float*)d_in[6];
    const float* imp_sr  = (const float*)d_in[7];
    const float* pca_sr  = (const float*)d_in[8];
    const float* conf_tg = (const float*)d_in[9];
    const float* imp_tg  = (const float*)d_in[10];
    const float* pca_tg  = (const float*)d_in[11];
    const int* head_sr = (const int*)d_in[12];
    const int* tail_sr = (const int*)d_in[13];
    const int* rel_i_sr = (const int*)d_in[14];
    const int* head_tg = (const int*)d_in[15];
    const int* tail_tg = (const int*)d_in[16];
    const int* rel_i_tg = (const int*)d_in[17];

    float* out = (float*)d_out;

    const int total = 2 * E_ * E_;           // 50,000,000 floats
    const int nthreads = total / 16;         // 3,125,000
    int init_blocks = (nthreads + 255) / 256;
    init_kernel<<<init_blocks, 256, 0, stream>>>(out, nthreads);

    // 2N triples, 4 per wave, 4 waves per block
    int waves = (2 * N_) / 4;                // 100,000
    int tri_blocks = (waves + 3) / 4;        // 25,000
    triple_kernel<<<tri_blocks, 256, 0, stream>>>(
        ent_sr, rel_sr, relw_sr, conf_sr, imp_sr, pca_sr,
        head_sr, tail_sr, rel_i_sr,
        ent_tg, rel_tg, relw_tg, conf_tg, imp_tg, pca_tg,
        head_tg, tail_tg, rel_i_tg,
        out);
}